// Round 4
// baseline (1129.901 us; speedup 1.0000x reference)
//
#include <hip/hip_runtime.h>
#include <hip/hip_bf16.h>
#include <cstdint>
#include <cstddef>
#include <math.h>
#include <type_traits>

typedef __bf16 bf16;
typedef __bf16 bf16x8 __attribute__((ext_vector_type(8)));
typedef float  f32x4  __attribute__((ext_vector_type(4)));

// Shapes (fixed): B=4, T=4096, D=1024, H=8, DH=128, BUCKETS=64, BSZ=64, BH=32
// ws: q/k/v (bf16, 32 MiB each) + xa (32 MiB: first x-as-bf16, later attn out)
// R (512 KiB fp32) lives in the head of d_out (fully overwritten by final GEMM).

// ---------------------------------------------------------------------------
// Runtime input-dtype detection. Interpret the first 64 half-words of x as
// bf16: genuine bf16 N(0,1) never reaches |v|>=2^10 (exp>=137); fp32 buffers
// put mantissa bits there -> random exponents, hit w.p. 1-0.53^64.
// Wave-uniform (all waves read the same 64 half-words).
// ---------------------------------------------------------------------------
__device__ inline bool input_is_fp32(const void* x) {
  const unsigned short* u = (const unsigned short*)x;
  const int lane = threadIdx.x & 63;
  const int e = (u[lane] >> 7) & 0xFF;
  return __ballot(e >= 137) != 0ULL;
}

template<typename T>
__device__ inline float ldf(const void* p, size_t i) {
  if constexpr (std::is_same<T, float>::value) return ((const float*)p)[i];
  else return (float)((const bf16*)p)[i];
}

template<typename T>
__device__ inline bf16x8 ld8bf(const void* p, size_t i) {
  if constexpr (std::is_same<T, float>::value) {
    const f32x4* q = (const f32x4*)((const float*)p + i);
    const f32x4 a = q[0], b = q[1];
    bf16x8 r;
    r[0]=(bf16)a[0]; r[1]=(bf16)a[1]; r[2]=(bf16)a[2]; r[3]=(bf16)a[3];
    r[4]=(bf16)b[0]; r[5]=(bf16)b[1]; r[6]=(bf16)b[2]; r[7]=(bf16)b[3];
    return r;
  } else {
    return *(const bf16x8*)((const bf16*)p + i);
  }
}

// ---------------------------------------------------------------------------
// x -> bf16 copy/cast into ws (16,777,216 elements). Branches internally on
// detected dtype; runs unconditionally (same work every call).
// ---------------------------------------------------------------------------
__global__ __launch_bounds__(256)
void convert_x(const void* __restrict__ x, bf16* __restrict__ dst) {
  const bool f32 = input_is_fp32(x);
  const size_t i = ((size_t)blockIdx.x * 256 + threadIdx.x) * 8;
  if (f32) *(bf16x8*)&dst[i] = ld8bf<float>(x, i);
  else     *(bf16x8*)&dst[i] = ld8bf<bf16 >(x, i);
}

// ---------------------------------------------------------------------------
// GEMM: C[m][n] = sum_k A[m][k] * B[n][k].  A is internal bf16; B/bias are the
// external dtype TB. 128x128 tile, BK=32, 4 waves, 16x16x32 MFMA, fp32 acc.
// EPI=0: scatter into bucketed q/k/v.  EPI=1: bias add, row-major C0 (dtype TB).
// Variant executes only if detected dtype matches `expect`.
// ---------------------------------------------------------------------------
template<int EPI, typename TB>
__global__ __launch_bounds__(256)
void gemm_bt(const bf16* __restrict__ A, const void* __restrict__ Bm,
             const void* __restrict__ bias,
             void* __restrict__ C0, bf16* __restrict__ C1, bf16* __restrict__ C2,
             const void* __restrict__ xdet, int expect, int M, int N, int K)
{
  if ((int)input_is_fp32(xdet) != expect) return;

  __shared__ __align__(16) bf16 As[128*32];
  __shared__ __align__(16) bf16 Bs[128*32];
  const int tid  = threadIdx.x;
  const int wave = tid >> 6, lane = tid & 63;
  const int m0 = blockIdx.y * 128, n0 = blockIdx.x * 128;
  const int wm = (wave >> 1) * 64, wn = (wave & 1) * 64;
  const int ar = tid >> 2;
  const int ac = (tid & 3) * 8;
  const int fr = lane & 15;
  const int fk = (lane >> 4) * 8;

  f32x4 acc[4][4];
  #pragma unroll
  for (int a = 0; a < 4; ++a)
    #pragma unroll
    for (int b = 0; b < 4; ++b) { f32x4 z = {0.f, 0.f, 0.f, 0.f}; acc[a][b] = z; }

  for (int k0 = 0; k0 < K; k0 += 32) {
    __syncthreads();
    *(bf16x8*)&As[ar*32 + ac]      = *(const bf16x8*)&A[(size_t)(m0+ar)*K    + k0 + ac];
    *(bf16x8*)&As[(ar+64)*32 + ac] = *(const bf16x8*)&A[(size_t)(m0+ar+64)*K + k0 + ac];
    *(bf16x8*)&Bs[ar*32 + ac]      = ld8bf<TB>(Bm, (size_t)(n0+ar)*K    + k0 + ac);
    *(bf16x8*)&Bs[(ar+64)*32 + ac] = ld8bf<TB>(Bm, (size_t)(n0+ar+64)*K + k0 + ac);
    __syncthreads();
    bf16x8 af[4], bfr[4];
    #pragma unroll
    for (int t = 0; t < 4; ++t) {
      af[t]  = *(const bf16x8*)&As[(wm + t*16 + fr)*32 + fk];
      bfr[t] = *(const bf16x8*)&Bs[(wn + t*16 + fr)*32 + fk];
    }
    #pragma unroll
    for (int tm = 0; tm < 4; ++tm)
      #pragma unroll
      for (int tn = 0; tn < 4; ++tn)
        acc[tm][tn] = __builtin_amdgcn_mfma_f32_16x16x32_bf16(af[tm], bfr[tn], acc[tm][tn], 0, 0, 0);
  }

  // C/D layout (m89/m91 verified): col = lane&15, row = (lane>>4)*4 + reg
  const int cn = lane & 15, cr = (lane >> 4) * 4;
  #pragma unroll
  for (int tm = 0; tm < 4; ++tm) {
    #pragma unroll
    for (int tn = 0; tn < 4; ++tn) {
      #pragma unroll
      for (int r = 0; r < 4; ++r) {
        const int m = m0 + wm + tm*16 + cr + r;
        const int n = n0 + wn + tn*16 + cn;
        float val = acc[tm][tn][r];
        if (EPI == 0) {
          const int b = m >> 12, t = m & 4095;
          const int u = t >> 6,  i = t & 63;
          const int sel = n >> 10, c = n & 1023;
          const int h = c >> 7, e = c & 127;
          bf16* dst = (sel == 0) ? (bf16*)C0 : ((sel == 1) ? C1 : C2);
          dst[(((size_t)((b*8 + h)*64 + u))*64 + i)*128 + e] = (bf16)val;
        } else {
          val += ldf<TB>(bias, n);
          if constexpr (std::is_same<TB, float>::value)
            ((float*)C0)[(size_t)m*N + n] = val;
          else
            ((bf16*)C0)[(size_t)m*N + n] = (bf16)val;
        }
      }
    }
  }
}

// ---------------------------------------------------------------------------
// Sinkhorn sorting matrix R per bh (32 blocks). Gumbel inner expr in fp64
// (fp32 cancels catastrophically when noise ~ 1.0).
// ---------------------------------------------------------------------------
template<typename TB>
__global__ __launch_bounds__(256)
void sinkhorn_R(const bf16* __restrict__ k_ws, const void* __restrict__ sort_w,
                const void* __restrict__ noise, float* __restrict__ R_buf,
                const void* __restrict__ xdet, int expect)
{
  if ((int)input_is_fp32(xdet) != expect) return;

  const int bh = blockIdx.x, h = bh & 7, tid = threadIdx.x;
  __shared__ float bkr[64*128];
  __shared__ float R[64*65];
  const bf16* kbase = k_ws + (size_t)bh * (64*64*128);

  for (int f = tid; f < 64*128; f += 256) {
    const int u = f >> 7, e = f & 127;
    const bf16* p = kbase + (size_t)u*8192 + e;
    float s = 0.f;
    for (int i = 0; i < 64; ++i) s += (float)p[i*128];
    bkr[f] = s;
  }
  __syncthreads();

  for (int f = tid; f < 64*64; f += 256) {
    const int u = f >> 6, v = f & 63;
    float s = 0.f;
    for (int e = 0; e < 128; ++e)
      s += bkr[u*128 + e] * ldf<TB>(sort_w, (size_t)h*128*64 + (size_t)e*64 + v);
    s = fmaxf(s, 0.f);
    const float r  = logf(s + 1e-6f);
    const double nz = (double)ldf<TB>(noise, ((size_t)bh*64 + u)*64 + v);
    const double t1 = log(nz + 1e-4);
    const double t2 = fmax(-t1 + 1e-4, 1e-30);
    const float g = (float)(-log(t2));
    R[u*65 + v] = (r + g) * (1.f / 0.75f);
  }
  __syncthreads();

  for (int it = 0; it < 5; ++it) {
    if (tid < 64) {
      float mx = -1e30f;
      for (int v = 0; v < 64; ++v) mx = fmaxf(mx, R[tid*65 + v]);
      float s = 0.f;
      for (int v = 0; v < 64; ++v) s += expf(R[tid*65 + v] - mx);
      const float l = mx + logf(s);
      for (int v = 0; v < 64; ++v) R[tid*65 + v] -= l;
    }
    __syncthreads();
    if (tid < 64) {
      float mx = -1e30f;
      for (int u = 0; u < 64; ++u) mx = fmaxf(mx, R[u*65 + tid]);
      float s = 0.f;
      for (int u = 0; u < 64; ++u) s += expf(R[u*65 + tid] - mx);
      const float l = mx + logf(s);
      for (int u = 0; u < 64; ++u) R[u*65 + tid] -= l;
    }
    __syncthreads();
  }

  for (int f = tid; f < 64*64; f += 256) {
    const int u = f >> 6, v = f & 63;
    R_buf[(size_t)bh*4096 + f] = (u > v) ? expf(R[u*65 + v]) : 0.f;
  }
}

// ---------------------------------------------------------------------------
// Bucketed attention (all-internal dtypes; single launch). One block per
// (bh,u). k_re/v_re prefix mix -> dots -> softmax -> PV -> (b,t,d) layout.
// ---------------------------------------------------------------------------
__global__ __launch_bounds__(256)
void attn_bucket(const bf16* __restrict__ q_ws, const bf16* __restrict__ k_ws,
                 const bf16* __restrict__ v_ws, const float* __restrict__ R_buf,
                 bf16* __restrict__ aout)
{
  const int u = blockIdx.x, bh = blockIdx.y, tid = threadIdx.x;
  __shared__ float kre[64*132];
  __shared__ float vre[64*132];
  __shared__ float sc [64*133];
  __shared__ __align__(16) bf16 qs[64*132];
  __shared__ __align__(16) bf16 ku[64*136];
  __shared__ __align__(16) bf16 vu[64*128];
  __shared__ float Rrow[64];

  const size_t tile = ((size_t)bh*64 + u) * 8192;
  {
    const int base = tid * 8;
    #pragma unroll
    for (int r = 0; r < 4; ++r) {
      const int f = r*2048 + base;
      const int i = f >> 7, e = f & 127;
      bf16x8 qv = *(const bf16x8*)&q_ws[tile + f];
      bf16x8 kv = *(const bf16x8*)&k_ws[tile + f];
      bf16x8 vv = *(const bf16x8*)&v_ws[tile + f];
      *(bf16x8*)&vu[i*128 + e] = vv;
      #pragma unroll
      for (int j = 0; j < 8; ++j) { qs[i*132 + e + j] = qv[j]; ku[i*136 + e + j] = kv[j]; }
    }
  }
  if (tid < 64) Rrow[tid] = R_buf[(size_t)bh*4096 + (size_t)u*64 + tid];
  __syncthreads();

  {
    float ak[32], av[32];
    #pragma unroll
    for (int r = 0; r < 32; ++r) { ak[r] = 0.f; av[r] = 0.f; }
    for (int v = 0; v < u; ++v) {
      const float rv = Rrow[v];
      const bf16* kp = k_ws + ((size_t)bh*64 + v)*8192;
      const bf16* vp = v_ws + ((size_t)bh*64 + v)*8192;
      #pragma unroll
      for (int r = 0; r < 4; ++r) {
        bf16x8 kv = *(const bf16x8*)&kp[r*2048 + tid*8];
        bf16x8 vv = *(const bf16x8*)&vp[r*2048 + tid*8];
        #pragma unroll
        for (int j = 0; j < 8; ++j) {
          ak[r*8 + j] += rv * (float)kv[j];
          av[r*8 + j] += rv * (float)vv[j];
        }
      }
    }
    #pragma unroll
    for (int r = 0; r < 4; ++r) {
      #pragma unroll
      for (int j = 0; j < 8; ++j) {
        const int f = r*2048 + tid*8 + j;
        const int i = f >> 7, e = f & 127;
        kre[i*132 + e] = ak[r*8 + j];
        vre[i*132 + e] = av[r*8 + j];
      }
    }
  }
  __syncthreads();

  {
    const int i = tid >> 2, jc = tid & 3;
    float dacc[32];
    #pragma unroll
    for (int jj = 0; jj < 32; ++jj) dacc[jj] = 0.f;
    for (int e0 = 0; e0 < 128; e0 += 16) {
      float qc[16];
      #pragma unroll
      for (int t = 0; t < 16; ++t) qc[t] = (float)qs[i*132 + e0 + t];
      #pragma unroll
      for (int jj = 0; jj < 32; ++jj) {
        const int j = jc + jj*4;
        float s = 0.f;
        if (jj < 16) {
          const float* kp = &kre[j*132 + e0];
          #pragma unroll
          for (int t = 0; t < 16; ++t) s += qc[t] * kp[t];
        } else {
          const bf16* kp = &ku[(j - 64)*136 + e0];
          #pragma unroll
          for (int t = 0; t < 16; ++t) s += qc[t] * (float)kp[t];
        }
        dacc[jj] += s;
      }
    }
    #pragma unroll
    for (int jj = 0; jj < 32; ++jj) sc[i*133 + jc + jj*4] = dacc[jj] * 0.03125f;
  }
  __syncthreads();

  if (tid < 64) {
    float mx = -1e30f;
    for (int j = 0; j < 128; ++j) mx = fmaxf(mx, sc[tid*133 + j]);
    float s = 0.f;
    for (int j = 0; j < 128; ++j) { const float e = expf(sc[tid*133 + j] - mx); sc[tid*133 + j] = e; s += e; }
    const float inv = 1.f / s;
    for (int j = 0; j < 128; ++j) sc[tid*133 + j] *= inv;
  }
  __syncthreads();

  {
    const int i = tid >> 2, ec = tid & 3;
    float oacc[32];
    #pragma unroll
    for (int ee = 0; ee < 32; ++ee) oacc[ee] = 0.f;
    for (int j0 = 0; j0 < 128; j0 += 16) {
      float pc[16];
      #pragma unroll
      for (int t = 0; t < 16; ++t) pc[t] = sc[i*133 + j0 + t];
      if (j0 < 64) {
        #pragma unroll
        for (int t = 0; t < 16; ++t) {
          const float* vp = &vre[(j0 + t)*132];
          const float p = pc[t];
          #pragma unroll
          for (int ee = 0; ee < 32; ++ee) oacc[ee] += p * vp[ec + ee*4];
        }
      } else {
        #pragma unroll
        for (int t = 0; t < 16; ++t) {
          const bf16* vp = &vu[(j0 + t - 64)*128];
          const float p = pc[t];
          #pragma unroll
          for (int ee = 0; ee < 32; ++ee) oacc[ee] += p * (float)vp[ec + ee*4];
        }
      }
    }
    #pragma unroll
    for (int ee = 0; ee < 32; ++ee) kre[i*132 + ec + ee*4] = oacc[ee];
  }
  __syncthreads();
  {
    const int b = bh >> 3, h = bh & 7;
    for (int f = tid; f < 8192; f += 256) {
      const int i = f >> 7, e = f & 127;
      aout[((size_t)(b*4096 + u*64 + i))*1024 + h*128 + e] = (bf16)kre[i*132 + e];
    }
  }
}

// ---------------------------------------------------------------------------
extern "C" void kernel_launch(void* const* d_in, const int* in_sizes, int n_in,
                              void* d_out, int out_size, void* d_ws, size_t ws_size,
                              hipStream_t stream)
{
  (void)in_sizes; (void)n_in; (void)out_size; (void)ws_size;
  const void* x      = d_in[0];   // (4,4096,1024)        bf16 or fp32 (runtime-detected)
  const void* w_qkv  = d_in[1];   // (3072,1024)
  const void* sort_w = d_in[2];   // (1,8,128,64)
  const void* w_out  = d_in[3];   // (1024,1024)
  const void* b_out  = d_in[4];   // (1024,)
  const void* noise  = d_in[5];   // (32,64,64)

  char* ws = (char*)d_ws;
  const size_t TEN = (size_t)32*64*64*128;     // 16,777,216 elements
  bf16* q_ws = (bf16*)ws;
  bf16* k_ws = q_ws + TEN;
  bf16* v_ws = k_ws + TEN;
  bf16* xa_ws = v_ws + TEN;        // first: x as bf16; later: attention output
  float* R_buf = (float*)d_out;    // 512 KiB; overwritten by the final GEMM

  // 0) x -> bf16 (cast or copy, runtime-branched)
  convert_x<<<8192, 256, 0, stream>>>(x, xa_ws);
  // 1) qkv projection (dtype-dual on weights only; dead variant exits instantly)
  gemm_bt<0, bf16 ><<<dim3(24,128), 256, 0, stream>>>(xa_ws, w_qkv, nullptr, q_ws, k_ws, v_ws, x, 0, 16384, 3072, 1024);
  gemm_bt<0, float><<<dim3(24,128), 256, 0, stream>>>(xa_ws, w_qkv, nullptr, q_ws, k_ws, v_ws, x, 1, 16384, 3072, 1024);
  // 2) sinkhorn R
  sinkhorn_R<bf16 ><<<32, 256, 0, stream>>>(k_ws, sort_w, noise, R_buf, x, 0);
  sinkhorn_R<float><<<32, 256, 0, stream>>>(k_ws, sort_w, noise, R_buf, x, 1);
  // 3) bucketed attention (internal dtypes only) — overwrites xa_ws
  attn_bucket<<<dim3(64,32), 256, 0, stream>>>(q_ws, k_ws, v_ws, R_buf, xa_ws);
  // 4) output projection + bias (output dtype matches input dtype)
  gemm_bt<1, bf16 ><<<dim3(8,128), 256, 0, stream>>>(xa_ws, w_out, b_out, d_out, nullptr, nullptr, x, 0, 16384, 1024, 1024);
  gemm_bt<1, float><<<dim3(8,128), 256, 0, stream>>>(xa_ws, w_out, b_out, d_out, nullptr, nullptr, x, 1, 16384, 1024, 1024);
}

// Round 5
// 638.472 us; speedup vs baseline: 1.7697x; 1.7697x over previous
//
#include <hip/hip_runtime.h>
#include <hip/hip_bf16.h>
#include <cstdint>
#include <cstddef>
#include <math.h>
#include <type_traits>

typedef __bf16 bf16;
typedef __bf16 bf16x8 __attribute__((ext_vector_type(8)));
typedef float  f32x4  __attribute__((ext_vector_type(4)));

// Shapes: B=4, T=4096, D=1024, H=8, DH=128, BUCKETS=64, BSZ=64, BH=32
// ws (128 MiB): q[bh][u][i][e] | k[bh][u][i][e] | vT[bh][u][e][i] | xa (x-as-bf16, later attn out (b,t,d))
// d_out head scratch: R (512 KiB fp32) + bkr (1 MiB fp32) — dead before final GEMM writes d_out.

// ---------------------------------------------------------------------------
// Runtime input-dtype detection (inputs proven fp32 in round 4; keep dual-path).
// ---------------------------------------------------------------------------
__device__ inline bool input_is_fp32(const void* x) {
  const unsigned short* u = (const unsigned short*)x;
  const int lane = threadIdx.x & 63;
  const int e = (u[lane] >> 7) & 0xFF;
  return __ballot(e >= 137) != 0ULL;
}

template<typename T>
__device__ inline float ldf(const void* p, size_t i) {
  if constexpr (std::is_same<T, float>::value) return ((const float*)p)[i];
  else return (float)((const bf16*)p)[i];
}

template<typename T>
__device__ inline bf16x8 ld8bf(const void* p, size_t i) {
  if constexpr (std::is_same<T, float>::value) {
    const f32x4* q = (const f32x4*)((const float*)p + i);
    const f32x4 a = q[0], b = q[1];
    bf16x8 r;
    r[0]=(bf16)a[0]; r[1]=(bf16)a[1]; r[2]=(bf16)a[2]; r[3]=(bf16)a[3];
    r[4]=(bf16)b[0]; r[5]=(bf16)b[1]; r[6]=(bf16)b[2]; r[7]=(bf16)b[3];
    return r;
  } else {
    return *(const bf16x8*)((const bf16*)p + i);
  }
}

__global__ __launch_bounds__(256)
void convert_x(const void* __restrict__ x, bf16* __restrict__ dst) {
  const bool f32 = input_is_fp32(x);
  const size_t i = ((size_t)blockIdx.x * 256 + threadIdx.x) * 8;
  if (f32) *(bf16x8*)&dst[i] = ld8bf<float>(x, i);
  else     *(bf16x8*)&dst[i] = ld8bf<bf16 >(x, i);
}

// ---------------------------------------------------------------------------
// GEMM: C[m][n] = sum_k A[m][k]*B[n][k]. A internal bf16; B/bias external TB.
// 128x128 tile, BK=32, 4 waves, 16x16x32 MFMA.
// EPI=0: scatter into q/k (by [u][i][e]) and vT (by [u][e][i]).
// EPI=1: bias add, row-major C0 in dtype TB.
// ---------------------------------------------------------------------------
template<int EPI, typename TB>
__global__ __launch_bounds__(256)
void gemm_bt(const bf16* __restrict__ A, const void* __restrict__ Bm,
             const void* __restrict__ bias,
             void* __restrict__ C0, bf16* __restrict__ C1, bf16* __restrict__ C2,
             const void* __restrict__ xdet, int expect, int M, int N, int K)
{
  if ((int)input_is_fp32(xdet) != expect) return;

  __shared__ __align__(16) bf16 As[128*32];
  __shared__ __align__(16) bf16 Bs[128*32];
  const int tid  = threadIdx.x;
  const int wave = tid >> 6, lane = tid & 63;
  const int m0 = blockIdx.y * 128, n0 = blockIdx.x * 128;
  const int wm = (wave >> 1) * 64, wn = (wave & 1) * 64;
  const int ar = tid >> 2;
  const int ac = (tid & 3) * 8;
  const int fr = lane & 15;
  const int fk = (lane >> 4) * 8;

  f32x4 acc[4][4];
  #pragma unroll
  for (int a = 0; a < 4; ++a)
    #pragma unroll
    for (int b = 0; b < 4; ++b) { f32x4 z = {0.f, 0.f, 0.f, 0.f}; acc[a][b] = z; }

  for (int k0 = 0; k0 < K; k0 += 32) {
    __syncthreads();
    *(bf16x8*)&As[ar*32 + ac]      = *(const bf16x8*)&A[(size_t)(m0+ar)*K    + k0 + ac];
    *(bf16x8*)&As[(ar+64)*32 + ac] = *(const bf16x8*)&A[(size_t)(m0+ar+64)*K + k0 + ac];
    *(bf16x8*)&Bs[ar*32 + ac]      = ld8bf<TB>(Bm, (size_t)(n0+ar)*K    + k0 + ac);
    *(bf16x8*)&Bs[(ar+64)*32 + ac] = ld8bf<TB>(Bm, (size_t)(n0+ar+64)*K + k0 + ac);
    __syncthreads();
    bf16x8 af[4], bfr[4];
    #pragma unroll
    for (int t = 0; t < 4; ++t) {
      af[t]  = *(const bf16x8*)&As[(wm + t*16 + fr)*32 + fk];
      bfr[t] = *(const bf16x8*)&Bs[(wn + t*16 + fr)*32 + fk];
    }
    #pragma unroll
    for (int tm = 0; tm < 4; ++tm)
      #pragma unroll
      for (int tn = 0; tn < 4; ++tn)
        acc[tm][tn] = __builtin_amdgcn_mfma_f32_16x16x32_bf16(af[tm], bfr[tn], acc[tm][tn], 0, 0, 0);
  }

  const int cn = lane & 15, cr = (lane >> 4) * 4;
  #pragma unroll
  for (int tm = 0; tm < 4; ++tm) {
    #pragma unroll
    for (int tn = 0; tn < 4; ++tn) {
      #pragma unroll
      for (int r = 0; r < 4; ++r) {
        const int m = m0 + wm + tm*16 + cr + r;
        const int n = n0 + wn + tn*16 + cn;
        float val = acc[tm][tn][r];
        if (EPI == 0) {
          const int b = m >> 12, t = m & 4095;
          const int u = t >> 6,  i = t & 63;
          const int sel = n >> 10, c = n & 1023;
          const int h = c >> 7, e = c & 127;
          const size_t bhu = (size_t)((b*8 + h)*64 + u);
          if (sel == 0)      ((bf16*)C0)[(bhu*64 + i)*128 + e] = (bf16)val;    // q [u][i][e]
          else if (sel == 1) C1[(bhu*64 + i)*128 + e] = (bf16)val;             // k [u][i][e]
          else               C2[(bhu*128 + e)*64 + i] = (bf16)val;             // vT [u][e][i]
        } else {
          val += ldf<TB>(bias, n);
          if constexpr (std::is_same<TB, float>::value)
            ((float*)C0)[(size_t)m*N + n] = val;
          else
            ((bf16*)C0)[(size_t)m*N + n] = (bf16)val;
        }
      }
    }
  }
}

// ---------------------------------------------------------------------------
// bksum: bkr[bh][u][e] = sum_i k[bh][u][i][e]. grid (8,32), 128 threads.
// Vectorized bf16x8 loads (e-contiguous).
// ---------------------------------------------------------------------------
__global__ __launch_bounds__(128)
void bksum(const bf16* __restrict__ k_ws, float* __restrict__ bkr_g)
{
  const int ug = blockIdx.x, bh = blockIdx.y, t = threadIdx.x;
  const int ul = t >> 4, e0 = (t & 15) * 8;
  const int u = ug * 8 + ul;
  const bf16* p = k_ws + ((size_t)bh*64 + u)*8192 + e0;
  float acc[8];
  #pragma unroll
  for (int j = 0; j < 8; ++j) acc[j] = 0.f;
  for (int i = 0; i < 64; ++i) {
    bf16x8 kv = *(const bf16x8*)&p[i*128];
    #pragma unroll
    for (int j = 0; j < 8; ++j) acc[j] += (float)kv[j];
  }
  float* dst = bkr_g + (size_t)bh*8192 + u*128 + e0;
  #pragma unroll
  for (int j = 0; j < 8; ++j) dst[j] = acc[j];
}

// ---------------------------------------------------------------------------
// Sinkhorn R per bh (32 blocks, 256 threads). Gumbel inner expr in fp64.
// ---------------------------------------------------------------------------
template<typename TB>
__global__ __launch_bounds__(256)
void sinkhorn_R(const float* __restrict__ bkr_g, const void* __restrict__ sort_w,
                const void* __restrict__ noise, float* __restrict__ R_buf,
                const void* __restrict__ xdet, int expect)
{
  if ((int)input_is_fp32(xdet) != expect) return;

  const int bh = blockIdx.x, h = bh & 7, tid = threadIdx.x;
  __shared__ float bkr[64*128];
  __shared__ float ew[128*64];
  __shared__ float R[64*65];

  for (int f = tid; f < 64*128; f += 256) bkr[f] = bkr_g[(size_t)bh*8192 + f];
  for (int f = tid; f < 128*64; f += 256) ew[f] = ldf<TB>(sort_w, (size_t)h*8192 + f);
  __syncthreads();

  for (int f = tid; f < 64*64; f += 256) {
    const int u = f >> 6, v = f & 63;
    float s = 0.f;
    for (int e = 0; e < 128; ++e) s += bkr[u*128 + e] * ew[e*64 + v];
    s = fmaxf(s, 0.f);
    const float r  = logf(s + 1e-6f);
    const double nz = (double)ldf<TB>(noise, ((size_t)bh*64 + u)*64 + v);
    const double t1 = log(nz + 1e-4);
    const double t2 = fmax(-t1 + 1e-4, 1e-30);
    const float g = (float)(-log(t2));
    R[u*65 + v] = (r + g) * (1.f / 0.75f);
  }
  __syncthreads();

  for (int it = 0; it < 5; ++it) {
    if (tid < 64) {
      float mx = -1e30f;
      for (int v = 0; v < 64; ++v) mx = fmaxf(mx, R[tid*65 + v]);
      float s = 0.f;
      for (int v = 0; v < 64; ++v) s += expf(R[tid*65 + v] - mx);
      const float l = mx + logf(s);
      for (int v = 0; v < 64; ++v) R[tid*65 + v] -= l;
    }
    __syncthreads();
    if (tid < 64) {
      float mx = -1e30f;
      for (int u = 0; u < 64; ++u) mx = fmaxf(mx, R[u*65 + tid]);
      float s = 0.f;
      for (int u = 0; u < 64; ++u) s += expf(R[u*65 + tid] - mx);
      const float l = mx + logf(s);
      for (int u = 0; u < 64; ++u) R[u*65 + tid] -= l;
    }
    __syncthreads();
  }

  for (int f = tid; f < 64*64; f += 256) {
    const int u = f >> 6, v = f & 63;
    R_buf[(size_t)bh*4096 + f] = (u > v) ? expf(R[u*65 + v]) : 0.f;
  }
}

// ---------------------------------------------------------------------------
// MFMA bucketed attention. One block per (bh,u), 256 threads (4 waves).
// Phase 1 (VALU): k_re[i][e], v_reT[e][i] = R-weighted prefix mix, bf16 in LDS.
// Phase 2 (MFMA): dots 64x128 (K=128); Q/raw-K frags straight from global.
// Phase 3: softmax (probs -> bf16 pA, aliased over sc).
// Phase 4 (MFMA): PV with B = [v_reT; raw vT from global].
// LDS ~70 KB -> 2 blocks/CU. u reversed for load balance (work ~ u).
// ---------------------------------------------------------------------------
__global__ __launch_bounds__(256)
void attn_mfma(const bf16* __restrict__ q_ws, const bf16* __restrict__ k_ws,
               const bf16* __restrict__ vT_ws, const float* __restrict__ R_buf,
               bf16* __restrict__ aout)
{
  const int u = 63 - blockIdx.x, bh = blockIdx.y, tid = threadIdx.x;
  const int lane = tid & 63, wave = tid >> 6;
  const int fr = lane & 15, quad = lane >> 4;

  // LDS carve: kre(64x136 bf16) | vreT(128x72 bf16) | union{sc 64x132 f32, pA 64x136 bf16} | Rrow
  __shared__ __align__(16) unsigned char smem[17408 + 18432 + 33792 + 256];
  bf16*  kre  = (bf16*)smem;                          // row stride 136
  bf16*  vreT = (bf16*)(smem + 17408);                // row stride 72
  float* sc   = (float*)(smem + 17408 + 18432);       // row stride 132
  bf16*  pA   = (bf16*)(smem + 17408 + 18432);        // row stride 136 (alias)
  float* Rrow = (float*)(smem + 17408 + 18432 + 33792);

  const size_t tileq = ((size_t)bh*64 + u) * 8192;

  if (tid < 64) Rrow[tid] = R_buf[(size_t)bh*4096 + (size_t)u*64 + tid];
  __syncthreads();

  // ---- Phase 1: prefix mix (fp32 reg acc, bf16 LDS out) ----
  {
    float ak[32], av[32];
    #pragma unroll
    for (int r = 0; r < 32; ++r) { ak[r] = 0.f; av[r] = 0.f; }
    for (int v = 0; v < u; ++v) {
      const float rv = Rrow[v];
      const bf16* kp = k_ws  + ((size_t)bh*64 + v)*8192;
      const bf16* vp = vT_ws + ((size_t)bh*64 + v)*8192;
      #pragma unroll
      for (int r = 0; r < 4; ++r) {
        bf16x8 kv = *(const bf16x8*)&kp[r*2048 + tid*8];
        bf16x8 vv = *(const bf16x8*)&vp[r*2048 + tid*8];
        #pragma unroll
        for (int j = 0; j < 8; ++j) {
          ak[r*8 + j] += rv * (float)kv[j];
          av[r*8 + j] += rv * (float)vv[j];
        }
      }
    }
    #pragma unroll
    for (int r = 0; r < 4; ++r) {
      const int f = r*2048 + tid*8;
      { // kre: f -> (i = f>>7, e0 = f&127)
        bf16x8 w;
        #pragma unroll
        for (int j = 0; j < 8; ++j) w[j] = (bf16)ak[r*8 + j];
        *(bf16x8*)&kre[(f >> 7)*136 + (f & 127)] = w;
      }
      { // vreT: f -> (e = f>>6, i0 = f&63)
        bf16x8 w;
        #pragma unroll
        for (int j = 0; j < 8; ++j) w[j] = (bf16)av[r*8 + j];
        *(bf16x8*)&vreT[(f >> 6)*72 + (f & 63)] = w;
      }
    }
  }
  __syncthreads();

  // ---- Phase 2: dots (MFMA). Wave w owns j-slice [w*32, w*32+32). ----
  {
    f32x4 dacc[4][2];
    #pragma unroll
    for (int mt = 0; mt < 4; ++mt)
      #pragma unroll
      for (int nt = 0; nt < 2; ++nt) { f32x4 z = {0.f,0.f,0.f,0.f}; dacc[mt][nt] = z; }
    #pragma unroll
    for (int ks = 0; ks < 4; ++ks) {
      bf16x8 afr[4];
      #pragma unroll
      for (int mt = 0; mt < 4; ++mt)
        afr[mt] = *(const bf16x8*)&q_ws[tileq + (size_t)(mt*16 + fr)*128 + ks*32 + quad*8];
      #pragma unroll
      for (int nt = 0; nt < 2; ++nt) {
        const int j = wave*32 + nt*16 + fr;
        bf16x8 bfr;
        if (wave < 2) bfr = *(const bf16x8*)&kre[j*136 + ks*32 + quad*8];
        else          bfr = *(const bf16x8*)&k_ws[tileq + (size_t)(j - 64)*128 + ks*32 + quad*8];
        #pragma unroll
        for (int mt = 0; mt < 4; ++mt)
          dacc[mt][nt] = __builtin_amdgcn_mfma_f32_16x16x32_bf16(afr[mt], bfr, dacc[mt][nt], 0, 0, 0);
      }
    }
    #pragma unroll
    for (int mt = 0; mt < 4; ++mt)
      #pragma unroll
      for (int nt = 0; nt < 2; ++nt)
        #pragma unroll
        for (int r = 0; r < 4; ++r)
          sc[(mt*16 + quad*4 + r)*132 + wave*32 + nt*16 + fr] = dacc[mt][nt][r] * 0.03125f;
  }
  __syncthreads();

  // ---- Phase 3: softmax (4 threads per row; shfl groups of 4) ----
  {
    const int i = tid >> 2, jc = tid & 3;
    float pv[32];
    float mx = -1e30f;
    #pragma unroll
    for (int t = 0; t < 32; ++t) { pv[t] = sc[i*132 + jc + t*4]; mx = fmaxf(mx, pv[t]); }
    mx = fmaxf(mx, __shfl_xor(mx, 1));
    mx = fmaxf(mx, __shfl_xor(mx, 2));
    float s = 0.f;
    #pragma unroll
    for (int t = 0; t < 32; ++t) { pv[t] = expf(pv[t] - mx); s += pv[t]; }
    s += __shfl_xor(s, 1);
    s += __shfl_xor(s, 2);
    const float inv = 1.f / s;
    __syncthreads();                       // all sc reads done before pA alias-write
    #pragma unroll
    for (int t = 0; t < 32; ++t) pA[i*136 + jc + t*4] = (bf16)(pv[t] * inv);
  }
  __syncthreads();

  // ---- Phase 4: PV (MFMA). Wave w owns e-slice [w*32, w*32+32). ----
  {
    f32x4 oacc[4][2];
    #pragma unroll
    for (int mt = 0; mt < 4; ++mt)
      #pragma unroll
      for (int nt = 0; nt < 2; ++nt) { f32x4 z = {0.f,0.f,0.f,0.f}; oacc[mt][nt] = z; }
    #pragma unroll
    for (int ks = 0; ks < 4; ++ks) {       // j-chunk = ks*32
      bf16x8 afr[4];
      #pragma unroll
      for (int mt = 0; mt < 4; ++mt)
        afr[mt] = *(const bf16x8*)&pA[(mt*16 + fr)*136 + ks*32 + quad*8];
      #pragma unroll
      for (int nt = 0; nt < 2; ++nt) {
        const int e = wave*32 + nt*16 + fr;
        bf16x8 bfr;
        if (ks < 2) bfr = *(const bf16x8*)&vreT[e*72 + ks*32 + quad*8];
        else        bfr = *(const bf16x8*)&vT_ws[tileq + (size_t)e*64 + (ks - 2)*32 + quad*8];
        #pragma unroll
        for (int mt = 0; mt < 4; ++mt)
          oacc[mt][nt] = __builtin_amdgcn_mfma_f32_16x16x32_bf16(afr[mt], bfr, oacc[mt][nt], 0, 0, 0);
      }
    }
    __syncthreads();                       // pA frag reads done before reuse as out staging
    #pragma unroll
    for (int mt = 0; mt < 4; ++mt)
      #pragma unroll
      for (int nt = 0; nt < 2; ++nt)
        #pragma unroll
        for (int r = 0; r < 4; ++r)
          pA[(mt*16 + quad*4 + r)*136 + wave*32 + nt*16 + fr] = (bf16)oacc[mt][nt][r];
  }
  __syncthreads();

  // ---- Coalesced global write: (b, t, d) layout ----
  {
    const int b = bh >> 3, h = bh & 7;
    #pragma unroll
    for (int r = 0; r < 4; ++r) {
      const int f = r*2048 + tid*8;
      const int i = f >> 7, e0 = f & 127;
      bf16x8 w = *(const bf16x8*)&pA[i*136 + e0];
      *(bf16x8*)&aout[((size_t)(b*4096 + u*64 + i))*1024 + h*128 + e0] = w;
    }
  }
}

// ---------------------------------------------------------------------------
extern "C" void kernel_launch(void* const* d_in, const int* in_sizes, int n_in,
                              void* d_out, int out_size, void* d_ws, size_t ws_size,
                              hipStream_t stream)
{
  (void)in_sizes; (void)n_in; (void)out_size; (void)ws_size;
  const void* x      = d_in[0];   // (4,4096,1024)
  const void* w_qkv  = d_in[1];   // (3072,1024)
  const void* sort_w = d_in[2];   // (1,8,128,64)
  const void* w_out  = d_in[3];   // (1024,1024)
  const void* b_out  = d_in[4];   // (1024,)
  const void* noise  = d_in[5];   // (32,64,64)

  char* ws = (char*)d_ws;
  const size_t TEN = (size_t)32*64*64*128;     // 16,777,216 elements
  bf16* q_ws  = (bf16*)ws;
  bf16* k_ws  = q_ws + TEN;
  bf16* vT_ws = k_ws + TEN;                    // transposed [bh][u][e][i]
  bf16* xa_ws = vT_ws + TEN;                   // x-as-bf16, later attn out (b,t,d)
  // scratch in d_out head (fp32 out => d_out is 64 MB; even bf16 out = 32 MB fits)
  float* R_buf = (float*)d_out;                          // 512 KiB
  float* bkr_g = (float*)((char*)d_out + 524288);        // 1 MiB

  convert_x<<<8192, 256, 0, stream>>>(x, xa_ws);

  gemm_bt<0, bf16 ><<<dim3(24,128), 256, 0, stream>>>(xa_ws, w_qkv, nullptr, q_ws, k_ws, vT_ws, x, 0, 16384, 3072, 1024);
  gemm_bt<0, float><<<dim3(24,128), 256, 0, stream>>>(xa_ws, w_qkv, nullptr, q_ws, k_ws, vT_ws, x, 1, 16384, 3072, 1024);

  bksum<<<dim3(8,32), 128, 0, stream>>>(k_ws, bkr_g);

  sinkhorn_R<bf16 ><<<32, 256, 0, stream>>>(bkr_g, sort_w, noise, R_buf, x, 0);
  sinkhorn_R<float><<<32, 256, 0, stream>>>(bkr_g, sort_w, noise, R_buf, x, 1);

  attn_mfma<<<dim3(64,32), 256, 0, stream>>>(q_ws, k_ws, vT_ws, R_buf, xa_ws);

  gemm_bt<1, bf16 ><<<dim3(8,128), 256, 0, stream>>>(xa_ws, w_out, b_out, d_out, nullptr, nullptr, x, 0, 16384, 1024, 1024);
  gemm_bt<1, float><<<dim3(8,128), 256, 0, stream>>>(xa_ws, w_out, b_out, d_out, nullptr, nullptr, x, 1, 16384, 1024, 1024);
}

// Round 6
// 579.017 us; speedup vs baseline: 1.9514x; 1.1027x over previous
//
#include <hip/hip_runtime.h>
#include <hip/hip_bf16.h>
#include <cstdint>
#include <cstddef>
#include <math.h>
#include <type_traits>

typedef __bf16 bf16;
typedef __bf16 bf16x4 __attribute__((ext_vector_type(4)));
typedef __bf16 bf16x8 __attribute__((ext_vector_type(8)));
typedef float  f32x4  __attribute__((ext_vector_type(4)));

// Shapes: B=4, T=4096, D=1024, H=8, DH=128, BUCKETS=64, BSZ=64, BH=32
// ws (128 MiB): q[bh][u][i][e] | k[bh][u][i][e] | vT[bh][u][e][i] | xa
// d_out scratch (dead before final GEMM): R 512K | bkr 1M | wqkv_bf 6M
// wout_bf lives in k_ws (dead after attn).

__device__ inline bool input_is_fp32(const void* x) {
  const unsigned short* u = (const unsigned short*)x;
  const int lane = threadIdx.x & 63;
  const int e = (u[lane] >> 7) & 0xFF;
  return __ballot(e >= 137) != 0ULL;
}

__device__ inline float ldx(const void* p, size_t i, bool f32) {
  return f32 ? ((const float*)p)[i] : (float)((const bf16*)p)[i];
}

template<typename T>
__device__ inline bf16x8 ld8bf(const void* p, size_t i) {
  if constexpr (std::is_same<T, float>::value) {
    const f32x4* q = (const f32x4*)((const float*)p + i);
    const f32x4 a = q[0], b = q[1];
    bf16x8 r;
    r[0]=(bf16)a[0]; r[1]=(bf16)a[1]; r[2]=(bf16)a[2]; r[3]=(bf16)a[3];
    r[4]=(bf16)b[0]; r[5]=(bf16)b[1]; r[6]=(bf16)b[2]; r[7]=(bf16)b[3];
    return r;
  } else {
    return *(const bf16x8*)((const bf16*)p + i);
  }
}

// async global->LDS, 16 B per lane; LDS dest = wave-uniform base + lane*16
__device__ __forceinline__ void gload16(const void* g, void* l) {
  __builtin_amdgcn_global_load_lds(
      (__attribute__((address_space(1))) void*)g,
      (__attribute__((address_space(3))) void*)l, 16, 0, 0);
}

// ---------------------------------------------------------------------------
// dtype-flexible fp32/bf16 -> bf16 copy. One thread = 8 elements.
// ---------------------------------------------------------------------------
__global__ __launch_bounds__(256)
void convert_to_bf16(const void* __restrict__ src, bf16* __restrict__ dst,
                     const void* __restrict__ xdet) {
  const bool f32 = input_is_fp32(xdet);
  const size_t i = ((size_t)blockIdx.x * 256 + threadIdx.x) * 8;
  if (f32) *(bf16x8*)&dst[i] = ld8bf<float>(src, i);
  else     *(bf16x8*)&dst[i] = ld8bf<bf16 >(src, i);
}

// ---------------------------------------------------------------------------
// GEMM: C[m][n] = sum_k A[m][k]*B[n][k], both bf16 K-contiguous.
// 128x128 tile, BK=32, 4 waves, 16x16x32 MFMA, m97-style global_load_lds x16.
// EPI=0: scatter into q/k ([u][i][e]) and vT ([u][e][i], 8-B packed).
// EPI=1: bias add, row-major C0, output dtype = detected input dtype.
// ---------------------------------------------------------------------------
template<int EPI>
__global__ __launch_bounds__(256)
void gemm_bt(const bf16* __restrict__ A, const bf16* __restrict__ Bm,
             const void* __restrict__ bias,
             void* __restrict__ C0, bf16* __restrict__ C1, bf16* __restrict__ C2,
             const void* __restrict__ xdet, int M, int N, int K)
{
  __shared__ __align__(16) bf16 As[128*32];
  __shared__ __align__(16) bf16 Bs[128*32];
  const int tid  = threadIdx.x;
  const int wave = tid >> 6, lane = tid & 63;
  const int m0 = blockIdx.y * 128, n0 = blockIdx.x * 128;
  const int wm = (wave >> 1) * 64, wn = (wave & 1) * 64;
  const int fr = lane & 15;
  const int fk = (lane >> 4) * 8;

  // staging: wave w covers rows w*16..w*16+15 (and +64); lane l -> row w*16+(l>>2), col (l&3)*8
  const int srow = wave * 16 + (lane >> 2);
  const int scol = (lane & 3) * 8;
  const bf16* gA = A  + (size_t)(m0 + srow) * K + scol;
  const bf16* gB = Bm + (size_t)(n0 + srow) * K + scol;
  bf16* lA = &As[wave * 16 * 32];
  bf16* lB = &Bs[wave * 16 * 32];

  f32x4 acc[4][4];
  #pragma unroll
  for (int a = 0; a < 4; ++a)
    #pragma unroll
    for (int b = 0; b < 4; ++b) { f32x4 z = {0.f, 0.f, 0.f, 0.f}; acc[a][b] = z; }

  for (int k0 = 0; k0 < K; k0 += 32) {
    __syncthreads();
    gload16(gA + k0,                  lA);
    gload16(gA + (size_t)64*K + k0,   lA + 64*32);
    gload16(gB + k0,                  lB);
    gload16(gB + (size_t)64*K + k0,   lB + 64*32);
    __syncthreads();                  // compiler drains vmcnt before barrier
    bf16x8 af[4], bfr[4];
    #pragma unroll
    for (int t = 0; t < 4; ++t) {
      af[t]  = *(const bf16x8*)&As[(wm + t*16 + fr)*32 + fk];
      bfr[t] = *(const bf16x8*)&Bs[(wn + t*16 + fr)*32 + fk];
    }
    #pragma unroll
    for (int tm = 0; tm < 4; ++tm)
      #pragma unroll
      for (int tn = 0; tn < 4; ++tn)
        acc[tm][tn] = __builtin_amdgcn_mfma_f32_16x16x32_bf16(af[tm], bfr[tn], acc[tm][tn], 0, 0, 0);
  }

  // C/D layout: col = lane&15, row = (lane>>4)*4 + reg
  const int cn = lane & 15, cr = (lane >> 4) * 4;
  if constexpr (EPI == 0) {
    const int sel = n0 >> 10;               // block-uniform (n0 mult of 128)
    const int cb  = (n0 & 1023) + wn;
    #pragma unroll
    for (int tm = 0; tm < 4; ++tm) {
      const int m = m0 + wm + tm*16 + cr;
      const int b = m >> 12, t = m & 4095;
      const int u = t >> 6,  i = t & 63;    // i..i+3 stay in-bucket
      #pragma unroll
      for (int tn = 0; tn < 4; ++tn) {
        const int c = cb + tn*16 + cn;
        const int h = c >> 7, e = c & 127;
        const size_t bhu = (size_t)((b*8 + h)*64 + u);
        if (sel == 2) {                     // vT [u][e][i]: one 8-B store
          bf16x4 w;
          #pragma unroll
          for (int r = 0; r < 4; ++r) w[r] = (bf16)acc[tm][tn][r];
          *(bf16x4*)&C2[(bhu*128 + e)*64 + i] = w;
        } else {                            // q/k [u][i][e]
          bf16* dst = (sel == 0) ? (bf16*)C0 : C1;
          #pragma unroll
          for (int r = 0; r < 4; ++r)
            dst[(bhu*64 + i + r)*128 + e] = (bf16)acc[tm][tn][r];
        }
      }
    }
  } else {
    const bool f32o = input_is_fp32(xdet);
    #pragma unroll
    for (int tm = 0; tm < 4; ++tm) {
      #pragma unroll
      for (int tn = 0; tn < 4; ++tn) {
        #pragma unroll
        for (int r = 0; r < 4; ++r) {
          const int m = m0 + wm + tm*16 + cr + r;
          const int n = n0 + wn + tn*16 + cn;
          const float val = acc[tm][tn][r] + ldx(bias, n, f32o);
          if (f32o) ((float*)C0)[(size_t)m*N + n] = val;
          else      ((bf16*)C0)[(size_t)m*N + n] = (bf16)val;
        }
      }
    }
  }
}

// ---------------------------------------------------------------------------
// bksum: bkr[bh][u][e] = sum_i k[bh][u][i][e]. grid (8,32), 128 threads.
// ---------------------------------------------------------------------------
__global__ __launch_bounds__(128)
void bksum(const bf16* __restrict__ k_ws, float* __restrict__ bkr_g)
{
  const int ug = blockIdx.x, bh = blockIdx.y, t = threadIdx.x;
  const int ul = t >> 4, e0 = (t & 15) * 8;
  const int u = ug * 8 + ul;
  const bf16* p = k_ws + ((size_t)bh*64 + u)*8192 + e0;
  float acc[8];
  #pragma unroll
  for (int j = 0; j < 8; ++j) acc[j] = 0.f;
  for (int i = 0; i < 64; ++i) {
    bf16x8 kv = *(const bf16x8*)&p[i*128];
    #pragma unroll
    for (int j = 0; j < 8; ++j) acc[j] += (float)kv[j];
  }
  float* dst = bkr_g + (size_t)bh*8192 + u*128 + e0;
  #pragma unroll
  for (int j = 0; j < 8; ++j) dst[j] = acc[j];
}

// ---------------------------------------------------------------------------
// Sinkhorn R per bh (32 blocks, 256 threads). Gumbel inner expr in fp64.
// ---------------------------------------------------------------------------
__global__ __launch_bounds__(256)
void sinkhorn_R(const float* __restrict__ bkr_g, const void* __restrict__ sort_w,
                const void* __restrict__ noise, float* __restrict__ R_buf,
                const void* __restrict__ xdet)
{
  const bool f32 = input_is_fp32(xdet);
  const int bh = blockIdx.x, h = bh & 7, tid = threadIdx.x;
  __shared__ float bkr[64*128];
  __shared__ float ew[128*64];
  __shared__ float R[64*65];

  for (int f = tid; f < 64*128; f += 256) bkr[f] = bkr_g[(size_t)bh*8192 + f];
  for (int f = tid; f < 128*64; f += 256) ew[f] = ldx(sort_w, (size_t)h*8192 + f, f32);
  __syncthreads();

  for (int f = tid; f < 64*64; f += 256) {
    const int u = f >> 6, v = f & 63;
    float s = 0.f;
    for (int e = 0; e < 128; ++e) s += bkr[u*128 + e] * ew[e*64 + v];
    s = fmaxf(s, 0.f);
    const float r  = logf(s + 1e-6f);
    const double nz = (double)ldx(noise, ((size_t)bh*64 + u)*64 + v, f32);
    const double t1 = log(nz + 1e-4);
    const double t2 = fmax(-t1 + 1e-4, 1e-30);
    const float g = (float)(-log(t2));
    R[u*65 + v] = (r + g) * (1.f / 0.75f);
  }
  __syncthreads();

  for (int it = 0; it < 5; ++it) {
    if (tid < 64) {
      float mx = -1e30f;
      for (int v = 0; v < 64; ++v) mx = fmaxf(mx, R[tid*65 + v]);
      float s = 0.f;
      for (int v = 0; v < 64; ++v) s += expf(R[tid*65 + v] - mx);
      const float l = mx + logf(s);
      for (int v = 0; v < 64; ++v) R[tid*65 + v] -= l;
    }
    __syncthreads();
    if (tid < 64) {
      float mx = -1e30f;
      for (int u = 0; u < 64; ++u) mx = fmaxf(mx, R[u*65 + tid]);
      float s = 0.f;
      for (int u = 0; u < 64; ++u) s += expf(R[u*65 + tid] - mx);
      const float l = mx + logf(s);
      for (int u = 0; u < 64; ++u) R[u*65 + tid] -= l;
    }
    __syncthreads();
  }

  for (int f = tid; f < 64*64; f += 256) {
    const int u = f >> 6, v = f & 63;
    R_buf[(size_t)bh*4096 + f] = (u > v) ? expf(R[u*65 + v]) : 0.f;
  }
}

// ---------------------------------------------------------------------------
// MFMA bucketed attention. One block per (bh,u), 256 threads. (round-4 design)
// ---------------------------------------------------------------------------
__global__ __launch_bounds__(256)
void attn_mfma(const bf16* __restrict__ q_ws, const bf16* __restrict__ k_ws,
               const bf16* __restrict__ vT_ws, const float* __restrict__ R_buf,
               bf16* __restrict__ aout)
{
  const int u = 63 - blockIdx.x, bh = blockIdx.y, tid = threadIdx.x;
  const int lane = tid & 63, wave = tid >> 6;
  const int fr = lane & 15, quad = lane >> 4;

  __shared__ __align__(16) unsigned char smem[17408 + 18432 + 33792 + 256];
  bf16*  kre  = (bf16*)smem;                          // 64 x (stride 136)
  bf16*  vreT = (bf16*)(smem + 17408);                // 128 x (stride 72)
  float* sc   = (float*)(smem + 17408 + 18432);       // 64 x (stride 132)
  bf16*  pA   = (bf16*)(smem + 17408 + 18432);        // alias, stride 136
  float* Rrow = (float*)(smem + 17408 + 18432 + 33792);

  const size_t tileq = ((size_t)bh*64 + u) * 8192;

  if (tid < 64) Rrow[tid] = R_buf[(size_t)bh*4096 + (size_t)u*64 + tid];
  __syncthreads();

  {
    float ak[32], av[32];
    #pragma unroll
    for (int r = 0; r < 32; ++r) { ak[r] = 0.f; av[r] = 0.f; }
    for (int v = 0; v < u; ++v) {
      const float rv = Rrow[v];
      const bf16* kp = k_ws  + ((size_t)bh*64 + v)*8192;
      const bf16* vp = vT_ws + ((size_t)bh*64 + v)*8192;
      #pragma unroll
      for (int r = 0; r < 4; ++r) {
        bf16x8 kv = *(const bf16x8*)&kp[r*2048 + tid*8];
        bf16x8 vv = *(const bf16x8*)&vp[r*2048 + tid*8];
        #pragma unroll
        for (int j = 0; j < 8; ++j) {
          ak[r*8 + j] += rv * (float)kv[j];
          av[r*8 + j] += rv * (float)vv[j];
        }
      }
    }
    #pragma unroll
    for (int r = 0; r < 4; ++r) {
      const int f = r*2048 + tid*8;
      {
        bf16x8 w;
        #pragma unroll
        for (int j = 0; j < 8; ++j) w[j] = (bf16)ak[r*8 + j];
        *(bf16x8*)&kre[(f >> 7)*136 + (f & 127)] = w;
      }
      {
        bf16x8 w;
        #pragma unroll
        for (int j = 0; j < 8; ++j) w[j] = (bf16)av[r*8 + j];
        *(bf16x8*)&vreT[(f >> 6)*72 + (f & 63)] = w;
      }
    }
  }
  __syncthreads();

  {
    f32x4 dacc[4][2];
    #pragma unroll
    for (int mt = 0; mt < 4; ++mt)
      #pragma unroll
      for (int nt = 0; nt < 2; ++nt) { f32x4 z = {0.f,0.f,0.f,0.f}; dacc[mt][nt] = z; }
    #pragma unroll
    for (int ks = 0; ks < 4; ++ks) {
      bf16x8 afr[4];
      #pragma unroll
      for (int mt = 0; mt < 4; ++mt)
        afr[mt] = *(const bf16x8*)&q_ws[tileq + (size_t)(mt*16 + fr)*128 + ks*32 + quad*8];
      #pragma unroll
      for (int nt = 0; nt < 2; ++nt) {
        const int j = wave*32 + nt*16 + fr;
        bf16x8 bfr;
        if (wave < 2) bfr = *(const bf16x8*)&kre[j*136 + ks*32 + quad*8];
        else          bfr = *(const bf16x8*)&k_ws[tileq + (size_t)(j - 64)*128 + ks*32 + quad*8];
        #pragma unroll
        for (int mt = 0; mt < 4; ++mt)
          dacc[mt][nt] = __builtin_amdgcn_mfma_f32_16x16x32_bf16(afr[mt], bfr, dacc[mt][nt], 0, 0, 0);
      }
    }
    #pragma unroll
    for (int mt = 0; mt < 4; ++mt)
      #pragma unroll
      for (int nt = 0; nt < 2; ++nt)
        #pragma unroll
        for (int r = 0; r < 4; ++r)
          sc[(mt*16 + quad*4 + r)*132 + wave*32 + nt*16 + fr] = dacc[mt][nt][r] * 0.03125f;
  }
  __syncthreads();

  {
    const int i = tid >> 2, jc = tid & 3;
    float pv[32];
    float mx = -1e30f;
    #pragma unroll
    for (int t = 0; t < 32; ++t) { pv[t] = sc[i*132 + jc + t*4]; mx = fmaxf(mx, pv[t]); }
    mx = fmaxf(mx, __shfl_xor(mx, 1));
    mx = fmaxf(mx, __shfl_xor(mx, 2));
    float s = 0.f;
    #pragma unroll
    for (int t = 0; t < 32; ++t) { pv[t] = expf(pv[t] - mx); s += pv[t]; }
    s += __shfl_xor(s, 1);
    s += __shfl_xor(s, 2);
    const float inv = 1.f / s;
    __syncthreads();
    #pragma unroll
    for (int t = 0; t < 32; ++t) pA[i*136 + jc + t*4] = (bf16)(pv[t] * inv);
  }
  __syncthreads();

  {
    f32x4 oacc[4][2];
    #pragma unroll
    for (int mt = 0; mt < 4; ++mt)
      #pragma unroll
      for (int nt = 0; nt < 2; ++nt) { f32x4 z = {0.f,0.f,0.f,0.f}; oacc[mt][nt] = z; }
    #pragma unroll
    for (int ks = 0; ks < 4; ++ks) {
      bf16x8 afr[4];
      #pragma unroll
      for (int mt = 0; mt < 4; ++mt)
        afr[mt] = *(const bf16x8*)&pA[(mt*16 + fr)*136 + ks*32 + quad*8];
      #pragma unroll
      for (int nt = 0; nt < 2; ++nt) {
        const int e = wave*32 + nt*16 + fr;
        bf16x8 bfr;
        if (ks < 2) bfr = *(const bf16x8*)&vreT[e*72 + ks*32 + quad*8];
        else        bfr = *(const bf16x8*)&vT_ws[tileq + (size_t)e*64 + (ks - 2)*32 + quad*8];
        #pragma unroll
        for (int mt = 0; mt < 4; ++mt)
          oacc[mt][nt] = __builtin_amdgcn_mfma_f32_16x16x32_bf16(afr[mt], bfr, oacc[mt][nt], 0, 0, 0);
      }
    }
    __syncthreads();
    #pragma unroll
    for (int mt = 0; mt < 4; ++mt)
      #pragma unroll
      for (int nt = 0; nt < 2; ++nt)
        #pragma unroll
        for (int r = 0; r < 4; ++r)
          pA[(mt*16 + quad*4 + r)*136 + wave*32 + nt*16 + fr] = (bf16)oacc[mt][nt][r];
  }
  __syncthreads();

  {
    const int b = bh >> 3, h = bh & 7;
    #pragma unroll
    for (int r = 0; r < 4; ++r) {
      const int f = r*2048 + tid*8;
      const int i = f >> 7, e0 = f & 127;
      bf16x8 w = *(const bf16x8*)&pA[i*136 + e0];
      *(bf16x8*)&aout[((size_t)(b*4096 + u*64 + i))*1024 + h*128 + e0] = w;
    }
  }
}

// ---------------------------------------------------------------------------
extern "C" void kernel_launch(void* const* d_in, const int* in_sizes, int n_in,
                              void* d_out, int out_size, void* d_ws, size_t ws_size,
                              hipStream_t stream)
{
  (void)in_sizes; (void)n_in; (void)out_size; (void)ws_size;
  const void* x      = d_in[0];   // (4,4096,1024)
  const void* w_qkv  = d_in[1];   // (3072,1024)
  const void* sort_w = d_in[2];   // (1,8,128,64)
  const void* w_out  = d_in[3];   // (1024,1024)
  const void* b_out  = d_in[4];   // (1024,)
  const void* noise  = d_in[5];   // (32,64,64)

  char* ws = (char*)d_ws;
  const size_t TEN = (size_t)32*64*64*128;     // 16,777,216 elements
  bf16* q_ws  = (bf16*)ws;
  bf16* k_ws  = q_ws + TEN;
  bf16* vT_ws = k_ws + TEN;                    // [bh][u][e][i]
  bf16* xa_ws = vT_ws + TEN;                   // x-as-bf16, later attn out (b,t,d)
  // d_out head scratch (dead before gemm2 writes d_out):
  float* R_buf   = (float*)d_out;                           // 512 KiB
  float* bkr_g   = (float*)((char*)d_out + (512<<10));      // 1 MiB
  bf16*  wqkv_bf = (bf16*)((char*)d_out + (1536<<10));      // 6 MiB
  bf16*  wout_bf = k_ws;                                    // reused after attn

  convert_to_bf16<<<8192, 256, 0, stream>>>(x, xa_ws, x);
  convert_to_bf16<<<1536, 256, 0, stream>>>(w_qkv, wqkv_bf, x);

  gemm_bt<0><<<dim3(24,128), 256, 0, stream>>>(xa_ws, wqkv_bf, nullptr,
                                               q_ws, k_ws, vT_ws, x, 16384, 3072, 1024);

  bksum<<<dim3(8,32), 128, 0, stream>>>(k_ws, bkr_g);
  sinkhorn_R<<<32, 256, 0, stream>>>(bkr_g, sort_w, noise, R_buf, x);

  attn_mfma<<<dim3(64,32), 256, 0, stream>>>(q_ws, k_ws, vT_ws, R_buf, xa_ws);

  convert_to_bf16<<<512, 256, 0, stream>>>(w_out, wout_bf, x);
  gemm_bt<1><<<dim3(8,128), 256, 0, stream>>>(xa_ws, wout_bf, b_out,
                                              d_out, nullptr, nullptr, x, 16384, 1024, 1024);
}